// Round 7
// baseline (502.669 us; speedup 1.0000x reference)
//
#include <hip/hip_runtime.h>
#include <math.h>

// 3-layer GAT, N=50000, E=800000 (+N self loops).
// L0 collapsed to 2-dim aggregation; L1 GEMM (split-bf16 MFMA) before aggregation;
// h1 stored fp16 in a permuted row layout; L2 projection fused into edge1 epilogue.

typedef __attribute__((ext_vector_type(8))) short s16x8;
typedef __attribute__((ext_vector_type(4))) float f32x4;
typedef unsigned short u16;

__device__ __forceinline__ float wred_sum(float v){
  #pragma unroll
  for (int m = 32; m > 0; m >>= 1) v += __shfl_xor(v, m, 64);
  return v;
}
__device__ __forceinline__ void wred_sum4(float4& v){
  #pragma unroll
  for (int m = 32; m > 0; m >>= 1){
    v.x += __shfl_xor(v.x, m, 64);
    v.y += __shfl_xor(v.y, m, 64);
    v.z += __shfl_xor(v.z, m, 64);
    v.w += __shfl_xor(v.w, m, 64);
  }
}
__device__ __forceinline__ void wred_max4(float4& v){
  #pragma unroll
  for (int m = 32; m > 0; m >>= 1){
    v.x = fmaxf(v.x, __shfl_xor(v.x, m, 64));
    v.y = fmaxf(v.y, __shfl_xor(v.y, m, 64));
    v.z = fmaxf(v.z, __shfl_xor(v.z, m, 64));
    v.w = fmaxf(v.w, __shfl_xor(v.w, m, 64));
  }
}
__device__ __forceinline__ u16 bf16_rne(float x){
  unsigned int u = __float_as_uint(x);
  unsigned int r = u + 0x7FFFu + ((u >> 16) & 1u);
  return (u16)(r >> 16);
}

// ---------------- setup: deg init + W1 hi/lo transpose-convert + vs(=W0@a0) prep ----------------
__global__ __launch_bounds__(256) void k_setup(const float* __restrict__ W1, u16* __restrict__ WhT,
                                               u16* __restrict__ WlT,
                                               const float* __restrict__ W0, const float* __restrict__ as0,
                                               const float* __restrict__ ad0, float* __restrict__ vs,
                                               int* __restrict__ deg, int N, int nblk_deg){
  int b = blockIdx.x;
  if (b < nblk_deg){
    int i = b * 256 + threadIdx.x;
    if (i < N) deg[i] = 1;            // self loop
  } else if (b < nblk_deg + 256){
    int k = b - nblk_deg, j = threadIdx.x;
    float w = W1[k * 256 + j];
    u16 h = bf16_rne(w);
    float hf = __uint_as_float(((unsigned int)h) << 16);
    WhT[j * 256 + k] = h;
    WlT[j * 256 + k] = bf16_rne(w - hf);
  } else {
    int t = threadIdx.x;
    if (t < 8){
      int j = t >> 2, h = t & 3;
      float ss = 0.f, dd = 0.f;
      #pragma unroll 8
      for (int o = 0; o < 64; o++){
        float w = W0[j * 256 + h * 64 + o];
        ss = fmaf(w, as0[h * 64 + o], ss);
        dd = fmaf(w, ad0[h * 64 + o], dd);
      }
      vs[j * 4 + h]     = ss;   // src proj
      vs[8 + j * 4 + h] = dd;   // dst proj
    }
  }
}

__global__ __launch_bounds__(256) void k_hist(const int* __restrict__ dst, int E, int* deg){
  int e = blockIdx.x * 256 + threadIdx.x;
  if (e < E) atomicAdd(&deg[dst[e]], 1);
}

// scan + selfloop fused
__global__ __launch_bounds__(1024) void k_scan(const int* __restrict__ deg, int* rowptr,
                                               int* __restrict__ ssrc, int* __restrict__ cursor, int N){
  __shared__ int sb[1024];
  int t = threadIdx.x;
  int chunk = (N + 1023) >> 10;
  int lo = t * chunk, hi = min(lo + chunk, N);
  int s = 0;
  for (int i = lo; i < hi; i++) s += deg[i];
  sb[t] = s;
  __syncthreads();
  for (int off = 1; off < 1024; off <<= 1){
    int v = (t >= off) ? sb[t - off] : 0;
    __syncthreads();
    sb[t] += v;
    __syncthreads();
  }
  int run = (t == 0) ? 0 : sb[t - 1];
  for (int i = lo; i < hi; i++){
    rowptr[i] = run;
    ssrc[run] = i;          // self loop first in segment
    cursor[i] = run + 1;
    run += deg[i];
  }
  if (t == 1023) rowptr[N] = sb[1023];
}

__global__ __launch_bounds__(256) void k_scatter(const int* __restrict__ src, const int* __restrict__ dst,
                                                 int E, int* cursor, int* ssrc){
  int e = blockIdx.x * 256 + threadIdx.x;
  if (e < E){ int p = atomicAdd(&cursor[dst[e]], 1); ssrc[p] = src[e]; }
}

// ---------------- edge0: 2-dim aggregation, e recomputed from x; epilogue writes x1 = relu(agg@W0+b0) ----------------
__global__ __launch_bounds__(256) void k_edge0(const float* __restrict__ X, const float* __restrict__ vs,
                                               const float* __restrict__ W0, const float* __restrict__ b0,
                                               const int* __restrict__ rowptr, const int* __restrict__ ssrc,
                                               float* __restrict__ X1, int N){
  int lane = threadIdx.x & 63;
  int n = blockIdx.x * 4 + (threadIdx.x >> 6);
  if (n >= N) return;
  int start = rowptr[n], deg = rowptr[n + 1] - start;
  float4 va = ((const float4*)vs)[0], vb = ((const float4*)vs)[1];   // src coeffs for x0,x1
  float4 vc = ((const float4*)vs)[2], vd = ((const float4*)vs)[3];   // dst coeffs
  float2 xn = ((const float2*)X)[n];
  float4 ed4;
  ed4.x = fmaf(xn.x, vc.x, xn.y * vd.x); ed4.y = fmaf(xn.x, vc.y, xn.y * vd.y);
  ed4.z = fmaf(xn.x, vc.z, xn.y * vd.z); ed4.w = fmaf(xn.x, vc.w, xn.y * vd.w);

  float4 m4 = make_float4(-3.0e38f,-3.0e38f,-3.0e38f,-3.0e38f);
  float2 x_keep = make_float2(0.f, 0.f);
  float4 e_keep = make_float4(0.f,0.f,0.f,0.f);
  for (int i = lane; i < deg; i += 64){
    int s = ssrc[start + i];
    float2 xs = ((const float2*)X)[s];
    float4 e;
    e.x = fmaf(xs.x, va.x, fmaf(xs.y, vb.x, ed4.x));
    e.y = fmaf(xs.x, va.y, fmaf(xs.y, vb.y, ed4.y));
    e.z = fmaf(xs.x, va.z, fmaf(xs.y, vb.z, ed4.z));
    e.w = fmaf(xs.x, va.w, fmaf(xs.y, vb.w, ed4.w));
    e.x = fmaxf(e.x, 0.2f*e.x); e.y = fmaxf(e.y, 0.2f*e.y);
    e.z = fmaxf(e.z, 0.2f*e.z); e.w = fmaxf(e.w, 0.2f*e.w);
    x_keep = xs; e_keep = e;
    m4.x = fmaxf(m4.x, e.x); m4.y = fmaxf(m4.y, e.y);
    m4.z = fmaxf(m4.z, e.z); m4.w = fmaxf(m4.w, e.w);
  }
  wred_max4(m4);

  float4 den = make_float4(0.f,0.f,0.f,0.f);
  float4 a0  = make_float4(0.f,0.f,0.f,0.f);
  float4 a1  = make_float4(0.f,0.f,0.f,0.f);
  if (deg <= 64){
    if (lane < deg){
      float4 wt;
      wt.x = __expf(e_keep.x - m4.x); wt.y = __expf(e_keep.y - m4.y);
      wt.z = __expf(e_keep.z - m4.z); wt.w = __expf(e_keep.w - m4.w);
      den = wt;
      a0.x = wt.x*x_keep.x; a0.y = wt.y*x_keep.x; a0.z = wt.z*x_keep.x; a0.w = wt.w*x_keep.x;
      a1.x = wt.x*x_keep.y; a1.y = wt.y*x_keep.y; a1.z = wt.z*x_keep.y; a1.w = wt.w*x_keep.y;
    }
  } else {
    for (int i = lane; i < deg; i += 64){
      int s = ssrc[start + i];
      float2 xs = ((const float2*)X)[s];
      float4 e;
      e.x = fmaf(xs.x, va.x, fmaf(xs.y, vb.x, ed4.x));
      e.y = fmaf(xs.x, va.y, fmaf(xs.y, vb.y, ed4.y));
      e.z = fmaf(xs.x, va.z, fmaf(xs.y, vb.z, ed4.z));
      e.w = fmaf(xs.x, va.w, fmaf(xs.y, vb.w, ed4.w));
      e.x = fmaxf(e.x, 0.2f*e.x); e.y = fmaxf(e.y, 0.2f*e.y);
      e.z = fmaxf(e.z, 0.2f*e.z); e.w = fmaxf(e.w, 0.2f*e.w);
      float4 wt;
      wt.x = __expf(e.x - m4.x); wt.y = __expf(e.y - m4.y);
      wt.z = __expf(e.z - m4.z); wt.w = __expf(e.w - m4.w);
      den.x += wt.x; den.y += wt.y; den.z += wt.z; den.w += wt.w;
      a0.x = fmaf(wt.x, xs.x, a0.x); a0.y = fmaf(wt.y, xs.x, a0.y);
      a0.z = fmaf(wt.z, xs.x, a0.z); a0.w = fmaf(wt.w, xs.x, a0.w);
      a1.x = fmaf(wt.x, xs.y, a1.x); a1.y = fmaf(wt.y, xs.y, a1.y);
      a1.z = fmaf(wt.z, xs.y, a1.z); a1.w = fmaf(wt.w, xs.y, a1.w);
    }
  }
  wred_sum4(den); wred_sum4(a0); wred_sum4(a1);

  // all lanes hold reductions; epilogue: x1 row (cols 4l..4l+3), head = lane>>4
  int hh = lane >> 4;
  float invd = 1.f / (((hh==0)?den.x:(hh==1)?den.y:(hh==2)?den.z:den.w) + 1e-16f);
  float g0 = ((hh==0)?a0.x:(hh==1)?a0.y:(hh==2)?a0.z:a0.w) * invd;
  float g1 = ((hh==0)?a1.x:(hh==1)?a1.y:(hh==2)?a1.z:a1.w) * invd;
  float4 w0r = ((const float4*)W0)[lane];
  float4 w1r = ((const float4*)(W0 + 256))[lane];
  float4 bb  = ((const float4*)b0)[lane];
  float4 v;
  v.x = fmaxf(fmaf(g0, w0r.x, fmaf(g1, w1r.x, bb.x)), 0.f);
  v.y = fmaxf(fmaf(g0, w0r.y, fmaf(g1, w1r.y, bb.y)), 0.f);
  v.z = fmaxf(fmaf(g0, w0r.z, fmaf(g1, w1r.z, bb.z)), 0.f);
  v.w = fmaxf(fmaf(g0, w0r.w, fmaf(g1, w1r.w, bb.w)), 0.f);
  ((float4*)(X1 + (size_t)n * 256))[lane] = v;
}

// ---------------- L1 GEMM: h1 = x1 @ W1 (split-bf16 MFMA); h1 -> fp16 permuted; ES1/ED1 epilogue ----------------
// Permuted row layout: position p = lr*16 + c holds column c*16 + lr.
__global__ __launch_bounds__(256) void k_l1_mfma(const float* __restrict__ X,
                                                 const u16* __restrict__ WhT, const u16* __restrict__ WlT,
                                                 const float* __restrict__ as_, const float* __restrict__ ad_,
                                                 u16* __restrict__ Hh16, float* __restrict__ ES,
                                                 float* __restrict__ ED, int N){
  __shared__ u16 Ah[64 * 32], Al[64 * 32];
  __shared__ u16 Bh[256 * 32], Bl[256 * 32];
  int t = threadIdx.x;
  int wv = t >> 6, lane = t & 63;
  int lr = lane & 15, lg = lane >> 4;
  int rb = blockIdx.x * 64;

  f32x4 acc[16];
  #pragma unroll
  for (int c = 0; c < 16; c++) acc[c] = (f32x4){0.f, 0.f, 0.f, 0.f};

  int arow = t >> 2, aseg = t & 3;
  int agrow = rb + arow;

  for (int ks = 0; ks < 8; ks++){
    int k0 = ks * 32;
    __syncthreads();
    {
      float xv[8];
      if (agrow < N){
        const float4* p = (const float4*)(X + (size_t)agrow * 256 + k0 + aseg * 8);
        float4 v0 = p[0], v1 = p[1];
        xv[0]=v0.x; xv[1]=v0.y; xv[2]=v0.z; xv[3]=v0.w;
        xv[4]=v1.x; xv[5]=v1.y; xv[6]=v1.z; xv[7]=v1.w;
      } else {
        #pragma unroll
        for (int i = 0; i < 8; i++) xv[i] = 0.f;
      }
      union { u16 us[8]; uint4 v; } ph, pl;
      #pragma unroll
      for (int i = 0; i < 8; i++){
        u16 h = bf16_rne(xv[i]);
        float hf = __uint_as_float(((unsigned int)h) << 16);
        ph.us[i] = h;
        pl.us[i] = bf16_rne(xv[i] - hf);
      }
      *(uint4*)&Ah[arow * 32 + aseg * 8] = ph.v;
      *(uint4*)&Al[arow * 32 + aseg * 8] = pl.v;
    }
    #pragma unroll
    for (int i = 0; i < 4; i++){
      int chunk = i * 256 + t;
      int j = chunk >> 2, seg = chunk & 3;
      *(uint4*)&Bh[j * 32 + seg * 8] = *(const uint4*)&WhT[j * 256 + k0 + seg * 8];
      *(uint4*)&Bl[j * 32 + seg * 8] = *(const uint4*)&WlT[j * 256 + k0 + seg * 8];
    }
    __syncthreads();
    s16x8 ah = *(const s16x8*)&Ah[(wv * 16 + lr) * 32 + lg * 8];
    s16x8 al = *(const s16x8*)&Al[(wv * 16 + lr) * 32 + lg * 8];
    #pragma unroll
    for (int c = 0; c < 16; c++){
      s16x8 bh = *(const s16x8*)&Bh[(c * 16 + lr) * 32 + lg * 8];
      s16x8 bl = *(const s16x8*)&Bl[(c * 16 + lr) * 32 + lg * 8];
      acc[c] = __builtin_amdgcn_mfma_f32_16x16x32_bf16(ah, bh, acc[c], 0, 0, 0);
      acc[c] = __builtin_amdgcn_mfma_f32_16x16x32_bf16(ah, bl, acc[c], 0, 0, 0);
      acc[c] = __builtin_amdgcn_mfma_f32_16x16x32_bf16(al, bh, acc[c], 0, 0, 0);
    }
  }

  // fp16 permuted write: row n, positions lr*16 + c (c=0..15) = cols c*16+lr
  #pragma unroll
  for (int q = 0; q < 4; q++){
    int n = rb + wv * 16 + lg * 4 + q;
    if (n < N){
      union { _Float16 h[16]; uint4 v[2]; } pk;
      #pragma unroll
      for (int c = 0; c < 16; c++) pk.h[c] = (_Float16)acc[c][q];
      uint4* dstp = (uint4*)(Hh16 + (size_t)n * 256 + lr * 16);
      dstp[0] = pk.v[0];
      dstp[1] = pk.v[1];
    }
  }
  // ES1/ED1 from full f32 acc
  float es_p[4][4], ed_p[4][4];
  #pragma unroll
  for (int h = 0; h < 4; h++)
    #pragma unroll
    for (int q = 0; q < 4; q++){ es_p[h][q] = 0.f; ed_p[h][q] = 0.f; }
  #pragma unroll
  for (int c = 0; c < 16; c++){
    float asv = as_[c * 16 + lr];
    float adv = ad_[c * 16 + lr];
    int h = c >> 2;
    #pragma unroll
    for (int q = 0; q < 4; q++){
      es_p[h][q] = fmaf(acc[c][q], asv, es_p[h][q]);
      ed_p[h][q] = fmaf(acc[c][q], adv, ed_p[h][q]);
    }
  }
  #pragma unroll
  for (int h = 0; h < 4; h++)
    #pragma unroll
    for (int q = 0; q < 4; q++){
      #pragma unroll
      for (int mk = 1; mk < 16; mk <<= 1){
        es_p[h][q] += __shfl_xor(es_p[h][q], mk, 64);
        ed_p[h][q] += __shfl_xor(ed_p[h][q], mk, 64);
      }
    }
  if (lr == 0){
    #pragma unroll
    for (int q = 0; q < 4; q++){
      int n = rb + wv * 16 + lg * 4 + q;
      if (n < N){
        #pragma unroll
        for (int h = 0; h < 4; h++){
          ES[n * 4 + h] = es_p[h][q];
          ED[n * 4 + h] = ed_p[h][q];
        }
      }
    }
  }
}

// ---------------- fp16 gather-aggregate helper (permuted layout, 8B/lane) ----------------
__device__ __forceinline__ void agg_rows16(const u16* __restrict__ Hh, const int* ssh, const float* wrow,
                                           int cl, int lane, float* acc){
  union Cv { uint2 u; _Float16 h[4]; };
  int j = 0;
  for (; j + 7 < cl; j += 8){
    Cv r0, r1, r2, r3, r4, r5, r6, r7;
    float w0=wrow[j],w1=wrow[j+1],w2=wrow[j+2],w3=wrow[j+3];
    float w4=wrow[j+4],w5=wrow[j+5],w6=wrow[j+6],w7=wrow[j+7];
    r0.u = *(const uint2*)(Hh + (size_t)ssh[j  ] * 256 + 4*lane);
    r1.u = *(const uint2*)(Hh + (size_t)ssh[j+1] * 256 + 4*lane);
    r2.u = *(const uint2*)(Hh + (size_t)ssh[j+2] * 256 + 4*lane);
    r3.u = *(const uint2*)(Hh + (size_t)ssh[j+3] * 256 + 4*lane);
    r4.u = *(const uint2*)(Hh + (size_t)ssh[j+4] * 256 + 4*lane);
    r5.u = *(const uint2*)(Hh + (size_t)ssh[j+5] * 256 + 4*lane);
    r6.u = *(const uint2*)(Hh + (size_t)ssh[j+6] * 256 + 4*lane);
    r7.u = *(const uint2*)(Hh + (size_t)ssh[j+7] * 256 + 4*lane);
    #pragma unroll
    for (int k = 0; k < 4; k++) acc[k] = fmaf(w0, (float)r0.h[k], acc[k]);
    #pragma unroll
    for (int k = 0; k < 4; k++) acc[k] = fmaf(w1, (float)r1.h[k], acc[k]);
    #pragma unroll
    for (int k = 0; k < 4; k++) acc[k] = fmaf(w2, (float)r2.h[k], acc[k]);
    #pragma unroll
    for (int k = 0; k < 4; k++) acc[k] = fmaf(w3, (float)r3.h[k], acc[k]);
    #pragma unroll
    for (int k = 0; k < 4; k++) acc[k] = fmaf(w4, (float)r4.h[k], acc[k]);
    #pragma unroll
    for (int k = 0; k < 4; k++) acc[k] = fmaf(w5, (float)r5.h[k], acc[k]);
    #pragma unroll
    for (int k = 0; k < 4; k++) acc[k] = fmaf(w6, (float)r6.h[k], acc[k]);
    #pragma unroll
    for (int k = 0; k < 4; k++) acc[k] = fmaf(w7, (float)r7.h[k], acc[k]);
  }
  for (; j + 3 < cl; j += 4){
    Cv r0, r1, r2, r3;
    float w0=wrow[j],w1=wrow[j+1],w2=wrow[j+2],w3=wrow[j+3];
    r0.u = *(const uint2*)(Hh + (size_t)ssh[j  ] * 256 + 4*lane);
    r1.u = *(const uint2*)(Hh + (size_t)ssh[j+1] * 256 + 4*lane);
    r2.u = *(const uint2*)(Hh + (size_t)ssh[j+2] * 256 + 4*lane);
    r3.u = *(const uint2*)(Hh + (size_t)ssh[j+3] * 256 + 4*lane);
    #pragma unroll
    for (int k = 0; k < 4; k++) acc[k] = fmaf(w0, (float)r0.h[k], acc[k]);
    #pragma unroll
    for (int k = 0; k < 4; k++) acc[k] = fmaf(w1, (float)r1.h[k], acc[k]);
    #pragma unroll
    for (int k = 0; k < 4; k++) acc[k] = fmaf(w2, (float)r2.h[k], acc[k]);
    #pragma unroll
    for (int k = 0; k < 4; k++) acc[k] = fmaf(w3, (float)r3.h[k], acc[k]);
  }
  for (; j < cl; ++j){
    Cv r0;
    float w0 = wrow[j];
    r0.u = *(const uint2*)(Hh + (size_t)ssh[j] * 256 + 4*lane);
    #pragma unroll
    for (int k = 0; k < 4; k++) acc[k] = fmaf(w0, (float)r0.h[k], acc[k]);
  }
}

// ---------------- edge1: one WAVE per dst, all 4 heads; epilogue fuses b1+relu+W2 -> P2{h2a,h2b,es2,ed2} ----------------
__global__ __launch_bounds__(256) void k_edge1(const u16* __restrict__ Hh16, const float* __restrict__ ES,
                                               const float* __restrict__ ED, const int* __restrict__ rowptr,
                                               const int* __restrict__ ssrc, const float* __restrict__ b1,
                                               const float* __restrict__ W2,
                                               const float* __restrict__ as2, const float* __restrict__ ad2,
                                               float* __restrict__ P2, int N){
  __shared__ int   ssh[4][64];
  __shared__ float wsh[4][4][68];
  __shared__ int   chmax_sh;
  int wave = threadIdx.x >> 6, lane = threadIdx.x & 63;
  int n = blockIdx.x * 4 + wave;
  bool active = (n < N);
  int myhead = lane & 3;                 // permuted layout: lane covers cols 64(l&3)+16j+(l>>2)
  int start = 0, deg = 0;
  float4 ed4 = make_float4(0.f,0.f,0.f,0.f);
  if (active){
    start = rowptr[n];
    deg   = rowptr[n + 1] - start;
    ed4   = ((const float4*)ED)[n];
  }

  float4 m4 = make_float4(-3.0e38f,-3.0e38f,-3.0e38f,-3.0e38f);
  int    s_keep = 0;
  float4 a_keep = make_float4(0.f,0.f,0.f,0.f);
  for (int i = lane; i < deg; i += 64){
    int s = ssrc[start + i];
    float4 e = ((const float4*)ES)[s];
    e.x += ed4.x; e.y += ed4.y; e.z += ed4.z; e.w += ed4.w;
    e.x = fmaxf(e.x, 0.2f*e.x); e.y = fmaxf(e.y, 0.2f*e.y);
    e.z = fmaxf(e.z, 0.2f*e.z); e.w = fmaxf(e.w, 0.2f*e.w);
    s_keep = s; a_keep = e;
    m4.x = fmaxf(m4.x, e.x); m4.y = fmaxf(m4.y, e.y);
    m4.z = fmaxf(m4.z, e.z); m4.w = fmaxf(m4.w, e.w);
  }
  wred_max4(m4);

  int mych = active ? ((deg + 63) >> 6) : 0;
  if (threadIdx.x == 0) chmax_sh = 0;
  __syncthreads();
  if (lane == 0) atomicMax(&chmax_sh, mych);
  __syncthreads();
  int nch = chmax_sh;

  float accv[4] = {0.f, 0.f, 0.f, 0.f};
  float4 den = make_float4(0.f,0.f,0.f,0.f);

  if (nch == 1){
    float4 wt = make_float4(0.f,0.f,0.f,0.f);
    if (active && lane < deg){
      wt.x = __expf(a_keep.x - m4.x); wt.y = __expf(a_keep.y - m4.y);
      wt.z = __expf(a_keep.z - m4.z); wt.w = __expf(a_keep.w - m4.w);
    }
    den = wt;
    ssh[wave][lane] = s_keep;
    wsh[wave][0][lane] = wt.x; wsh[wave][1][lane] = wt.y;
    wsh[wave][2][lane] = wt.z; wsh[wave][3][lane] = wt.w;
    __syncthreads();
    if (active)
      agg_rows16(Hh16, ssh[wave], wsh[wave][myhead], deg, lane, accv);
    __syncthreads();
  } else {
    for (int c = 0; c < nch; c++){
      int base = c << 6;
      int i = base + lane;
      float4 wt = make_float4(0.f,0.f,0.f,0.f);
      int s = 0;
      if (active && i < deg){
        s = ssrc[start + i];
        float4 e = ((const float4*)ES)[s];
        e.x += ed4.x; e.y += ed4.y; e.z += ed4.z; e.w += ed4.w;
        e.x = fmaxf(e.x, 0.2f*e.x); e.y = fmaxf(e.y, 0.2f*e.y);
        e.z = fmaxf(e.z, 0.2f*e.z); e.w = fmaxf(e.w, 0.2f*e.w);
        wt.x = __expf(e.x - m4.x); wt.y = __expf(e.y - m4.y);
        wt.z = __expf(e.z - m4.z); wt.w = __expf(e.w - m4.w);
      }
      den.x += wt.x; den.y += wt.y; den.z += wt.z; den.w += wt.w;
      ssh[wave][lane] = s;
      wsh[wave][0][lane] = wt.x; wsh[wave][1][lane] = wt.y;
      wsh[wave][2][lane] = wt.z; wsh[wave][3][lane] = wt.w;
      __syncthreads();
      if (active && base < deg)
        agg_rows16(Hh16, ssh[wave], wsh[wave][myhead], min(deg - base, 64), lane, accv);
      __syncthreads();
    }
  }

  if (!active) return;
  wred_sum4(den);
  float d = (myhead==0)?den.x:(myhead==1)?den.y:(myhead==2)?den.z:den.w;
  float inv = 1.f / (d + 1e-16f);
  int c0 = 64 * (lane & 3) + (lane >> 2);   // col_j = c0 + 16j
  float p0 = 0.f, p1 = 0.f;
  #pragma unroll
  for (int j = 0; j < 4; j++){
    int col = c0 + 16 * j;
    float v = fmaxf(fmaf(accv[j], inv, b1[col]), 0.f);
    float2 w2 = ((const float2*)W2)[col];
    p0 = fmaf(v, w2.x, p0);
    p1 = fmaf(v, w2.y, p1);
  }
  p0 = wred_sum(p0); p1 = wred_sum(p1);
  if (lane == 0){
    float4 o;
    o.x = p0; o.y = p1;
    o.z = p0*as2[0] + p1*as2[1];
    o.w = p0*ad2[0] + p1*ad2[1];
    ((float4*)P2)[n] = o;
  }
}

// ---------------- edge2: H=1, O=2; P2 = {h2a,h2b,es2,ed2}; single 16B gather + fast path ----------------
__global__ __launch_bounds__(256) void k_edge2(const float* __restrict__ P2, const int* __restrict__ rowptr,
                                               const int* __restrict__ ssrc, const float* __restrict__ bias,
                                               float* __restrict__ Out, int N){
  int lane = threadIdx.x & 63;
  int n = blockIdx.x * 4 + (threadIdx.x >> 6);
  if (n >= N) return;
  int start = rowptr[n], deg = rowptr[n + 1] - start;
  float edn = ((const float4*)P2)[n].w;
  float m = -3.0e38f;
  float4 p_keep = make_float4(0.f,0.f,0.f,0.f);
  float  e_keep = 0.f;
  for (int i = lane; i < deg; i += 64){
    int s = ssrc[start + i];
    float4 p = ((const float4*)P2)[s];
    float a = p.z + edn; a = fmaxf(a, 0.2f * a);
    p_keep = p; e_keep = a;
    m = fmaxf(m, a);
  }
  #pragma unroll
  for (int mk = 32; mk > 0; mk >>= 1) m = fmaxf(m, __shfl_xor(m, mk, 64));

  float den = 0.f, a0 = 0.f, a1 = 0.f;
  if (deg <= 64){
    if (lane < deg){
      float w = __expf(e_keep - m);
      den = w; a0 = w * p_keep.x; a1 = w * p_keep.y;
    }
  } else {
    for (int i = lane; i < deg; i += 64){
      int s = ssrc[start + i];
      float4 p = ((const float4*)P2)[s];
      float a = p.z + edn; a = fmaxf(a, 0.2f * a);
      float w = __expf(a - m);
      den += w;
      a0 = fmaf(w, p.x, a0);
      a1 = fmaf(w, p.y, a1);
    }
  }
  den = wred_sum(den); a0 = wred_sum(a0); a1 = wred_sum(a1);
  if (lane == 0){
    float inv = 1.f / (den + 1e-16f);
    Out[n*2]     = fmaxf(a0 * inv + bias[0], 0.f);
    Out[n*2 + 1] = fmaxf(a1 * inv + bias[1], 0.f);
  }
}

extern "C" void kernel_launch(void* const* d_in, const int* in_sizes, int n_in,
                              void* d_out, int out_size, void* d_ws, size_t ws_size,
                              hipStream_t stream) {
  const float* x   = (const float*)d_in[0];
  const int*   ei  = (const int*)  d_in[1];
  const float* W0  = (const float*)d_in[2];
  const float* as0 = (const float*)d_in[3];
  const float* ad0 = (const float*)d_in[4];
  const float* b0  = (const float*)d_in[5];
  const float* W1  = (const float*)d_in[6];
  const float* as1 = (const float*)d_in[7];
  const float* ad1 = (const float*)d_in[8];
  const float* b1  = (const float*)d_in[9];
  const float* W2  = (const float*)d_in[10];
  const float* as2 = (const float*)d_in[11];
  const float* ad2 = (const float*)d_in[12];
  const float* b2  = (const float*)d_in[13];

  int N = in_sizes[0] / 2;
  int E = in_sizes[1] / 2;
  const int* src = ei;
  const int* dst = ei + E;

  char* ws = (char*)d_ws;
  size_t off = 0;
  auto alc = [&](size_t bytes){ size_t o = off; off += (bytes + 255) & ~(size_t)255; return o; };
  int*   deg    = (int*)(ws + alc((size_t)N * 4));
  int*   rowptr = (int*)(ws + alc((size_t)(N + 1) * 4));
  int*   cursor = (int*)(ws + alc((size_t)N * 4));
  int*   ssrc   = (int*)(ws + alc((size_t)(E + N) * 4));
  float* X1     = (float*)(ws + alc((size_t)N * 256 * 4));
  u16*   Hh16   = (u16*)  (ws + alc((size_t)N * 256 * 2));
  float* es1    = (float*)(ws + alc((size_t)N * 4 * 4));
  float* ed1    = (float*)(ws + alc((size_t)N * 4 * 4));
  float* P2     = (float*)(ws + alc((size_t)N * 4 * 4));
  u16*   wht    = (u16*)  (ws + alc((size_t)256 * 256 * 2));
  u16*   wlt    = (u16*)  (ws + alc((size_t)256 * 256 * 2));
  float* vs     = (float*)(ws + alc(16 * 4));
  float* out    = (float*)d_out;

  int nblk_deg = (N + 255) / 256;

  k_setup  <<<nblk_deg + 257, 256, 0, stream>>>(W1, wht, wlt, W0, as0, ad0, vs, deg, N, nblk_deg);
  k_hist   <<<(E + 255)/256, 256, 0, stream>>>(dst, E, deg);
  k_scan   <<<1, 1024, 0, stream>>>(deg, rowptr, ssrc, cursor, N);
  k_scatter<<<(E + 255)/256, 256, 0, stream>>>(src, dst, E, cursor, ssrc);

  k_edge0  <<<(N + 3)/4, 256, 0, stream>>>(x, vs, W0, b0, rowptr, ssrc, X1, N);
  k_l1_mfma<<<(N + 63)/64, 256, 0, stream>>>(X1, wht, wlt, as1, ad1, Hh16, es1, ed1, N);
  k_edge1  <<<(N + 3)/4, 256, 0, stream>>>(Hh16, es1, ed1, rowptr, ssrc, b1, W2, as2, ad2, P2, N);
  k_edge2  <<<(N + 3)/4, 256, 0, stream>>>(P2, rowptr, ssrc, b2, out, N);
}

// Round 8
// 380.111 us; speedup vs baseline: 1.3224x; 1.3224x over previous
//
#include <hip/hip_runtime.h>
#include <math.h>

// 3-layer GAT, N=50000, E=800000 (+N self loops).
// L0 collapsed to 2-dim aggregation; L1 GEMM (split-bf16 MFMA) before aggregation;
// h1 stored fp16 in a permuted row layout; L2 projection fused into edge1 epilogue.
// CSR build uses a 3-level parallel scan (round-7's 1-block scan was 135 us).

typedef __attribute__((ext_vector_type(8))) short s16x8;
typedef __attribute__((ext_vector_type(4))) float f32x4;
typedef unsigned short u16;

__device__ __forceinline__ float wred_sum(float v){
  #pragma unroll
  for (int m = 32; m > 0; m >>= 1) v += __shfl_xor(v, m, 64);
  return v;
}
__device__ __forceinline__ void wred_sum4(float4& v){
  #pragma unroll
  for (int m = 32; m > 0; m >>= 1){
    v.x += __shfl_xor(v.x, m, 64);
    v.y += __shfl_xor(v.y, m, 64);
    v.z += __shfl_xor(v.z, m, 64);
    v.w += __shfl_xor(v.w, m, 64);
  }
}
__device__ __forceinline__ void wred_max4(float4& v){
  #pragma unroll
  for (int m = 32; m > 0; m >>= 1){
    v.x = fmaxf(v.x, __shfl_xor(v.x, m, 64));
    v.y = fmaxf(v.y, __shfl_xor(v.y, m, 64));
    v.z = fmaxf(v.z, __shfl_xor(v.z, m, 64));
    v.w = fmaxf(v.w, __shfl_xor(v.w, m, 64));
  }
}
__device__ __forceinline__ u16 bf16_rne(float x){
  unsigned int u = __float_as_uint(x);
  unsigned int r = u + 0x7FFFu + ((u >> 16) & 1u);
  return (u16)(r >> 16);
}

// ---------------- setup: deg init + W1 hi/lo transpose-convert + vs(=W0@a0) prep ----------------
__global__ __launch_bounds__(256) void k_setup(const float* __restrict__ W1, u16* __restrict__ WhT,
                                               u16* __restrict__ WlT,
                                               const float* __restrict__ W0, const float* __restrict__ as0,
                                               const float* __restrict__ ad0, float* __restrict__ vs,
                                               int* __restrict__ deg, int N, int nblk_deg){
  int b = blockIdx.x;
  if (b < nblk_deg){
    int i = b * 256 + threadIdx.x;
    if (i < N) deg[i] = 1;            // self loop
  } else if (b < nblk_deg + 256){
    int k = b - nblk_deg, j = threadIdx.x;
    float w = W1[k * 256 + j];
    u16 h = bf16_rne(w);
    float hf = __uint_as_float(((unsigned int)h) << 16);
    WhT[j * 256 + k] = h;
    WlT[j * 256 + k] = bf16_rne(w - hf);
  } else {
    int t = threadIdx.x;
    if (t < 8){
      int j = t >> 2, h = t & 3;
      float ss = 0.f, dd = 0.f;
      #pragma unroll 8
      for (int o = 0; o < 64; o++){
        float w = W0[j * 256 + h * 64 + o];
        ss = fmaf(w, as0[h * 64 + o], ss);
        dd = fmaf(w, ad0[h * 64 + o], dd);
      }
      vs[j * 4 + h]     = ss;   // src proj
      vs[8 + j * 4 + h] = dd;   // dst proj
    }
  }
}

__global__ __launch_bounds__(256) void k_hist(const int* __restrict__ dst, int E, int* deg){
  int e = blockIdx.x * 256 + threadIdx.x;
  if (e < E) atomicAdd(&deg[dst[e]], 1);
}

// ---------------- 3-level scan: local (2048/block) -> block offsets -> finish ----------------
__global__ __launch_bounds__(256) void k_scan_local(const int* __restrict__ deg, int* __restrict__ rowptr,
                                                    int* __restrict__ bsum, int N){
  __shared__ int sb[256];
  int t = threadIdx.x;
  int base = blockIdx.x * 2048 + t * 8;
  int d[8], s = 0;
  #pragma unroll
  for (int k = 0; k < 8; k++){
    d[k] = (base + k < N) ? deg[base + k] : 0;
    s += d[k];
  }
  sb[t] = s;
  __syncthreads();
  for (int off = 1; off < 256; off <<= 1){
    int v = (t >= off) ? sb[t - off] : 0;
    __syncthreads();
    sb[t] += v;
    __syncthreads();
  }
  int run = (t == 0) ? 0 : sb[t - 1];
  #pragma unroll
  for (int k = 0; k < 8; k++){
    if (base + k < N) rowptr[base + k] = run;
    run += d[k];
  }
  if (t == 255) bsum[blockIdx.x] = sb[255];
}

__global__ __launch_bounds__(64) void k_boff(const int* __restrict__ bsum, int* __restrict__ boff, int nb){
  __shared__ int sb[64];
  int t = threadIdx.x;
  int v = (t < nb) ? bsum[t] : 0;
  sb[t] = v;
  __syncthreads();
  for (int off = 1; off < 64; off <<= 1){
    int u = (t >= off) ? sb[t - off] : 0;
    __syncthreads();
    sb[t] += u;
    __syncthreads();
  }
  boff[t] = (t == 0) ? 0 : sb[t - 1];
  if (t == nb - 1) boff[nb] = sb[nb - 1];   // grand total
}

__global__ __launch_bounds__(256) void k_finish(int* __restrict__ rowptr, const int* __restrict__ boff,
                                                int* __restrict__ ssrc, int* __restrict__ cursor,
                                                int N, int nb){
  int i = blockIdx.x * 256 + threadIdx.x;
  if (i < N){
    int p = rowptr[i] + boff[i >> 11];
    rowptr[i] = p;
    ssrc[p] = i;          // self loop first in segment
    cursor[i] = p + 1;
  }
  if (i == 0) rowptr[N] = boff[nb];
}

__global__ __launch_bounds__(256) void k_scatter(const int* __restrict__ src, const int* __restrict__ dst,
                                                 int E, int* cursor, int* ssrc){
  int e = blockIdx.x * 256 + threadIdx.x;
  if (e < E){ int p = atomicAdd(&cursor[dst[e]], 1); ssrc[p] = src[e]; }
}

// ---------------- edge0: 2-dim aggregation, e recomputed from x; epilogue writes x1 = relu(agg@W0+b0) ----------------
__global__ __launch_bounds__(256) void k_edge0(const float* __restrict__ X, const float* __restrict__ vs,
                                               const float* __restrict__ W0, const float* __restrict__ b0,
                                               const int* __restrict__ rowptr, const int* __restrict__ ssrc,
                                               float* __restrict__ X1, int N){
  int lane = threadIdx.x & 63;
  int n = blockIdx.x * 4 + (threadIdx.x >> 6);
  if (n >= N) return;
  int start = rowptr[n], deg = rowptr[n + 1] - start;
  float4 va = ((const float4*)vs)[0], vb = ((const float4*)vs)[1];   // src coeffs for x0,x1
  float4 vc = ((const float4*)vs)[2], vd = ((const float4*)vs)[3];   // dst coeffs
  float2 xn = ((const float2*)X)[n];
  float4 ed4;
  ed4.x = fmaf(xn.x, vc.x, xn.y * vd.x); ed4.y = fmaf(xn.x, vc.y, xn.y * vd.y);
  ed4.z = fmaf(xn.x, vc.z, xn.y * vd.z); ed4.w = fmaf(xn.x, vc.w, xn.y * vd.w);

  float4 m4 = make_float4(-3.0e38f,-3.0e38f,-3.0e38f,-3.0e38f);
  float2 x_keep = make_float2(0.f, 0.f);
  float4 e_keep = make_float4(0.f,0.f,0.f,0.f);
  for (int i = lane; i < deg; i += 64){
    int s = ssrc[start + i];
    float2 xs = ((const float2*)X)[s];
    float4 e;
    e.x = fmaf(xs.x, va.x, fmaf(xs.y, vb.x, ed4.x));
    e.y = fmaf(xs.x, va.y, fmaf(xs.y, vb.y, ed4.y));
    e.z = fmaf(xs.x, va.z, fmaf(xs.y, vb.z, ed4.z));
    e.w = fmaf(xs.x, va.w, fmaf(xs.y, vb.w, ed4.w));
    e.x = fmaxf(e.x, 0.2f*e.x); e.y = fmaxf(e.y, 0.2f*e.y);
    e.z = fmaxf(e.z, 0.2f*e.z); e.w = fmaxf(e.w, 0.2f*e.w);
    x_keep = xs; e_keep = e;
    m4.x = fmaxf(m4.x, e.x); m4.y = fmaxf(m4.y, e.y);
    m4.z = fmaxf(m4.z, e.z); m4.w = fmaxf(m4.w, e.w);
  }
  wred_max4(m4);

  float4 den = make_float4(0.f,0.f,0.f,0.f);
  float4 a0  = make_float4(0.f,0.f,0.f,0.f);
  float4 a1  = make_float4(0.f,0.f,0.f,0.f);
  if (deg <= 64){
    if (lane < deg){
      float4 wt;
      wt.x = __expf(e_keep.x - m4.x); wt.y = __expf(e_keep.y - m4.y);
      wt.z = __expf(e_keep.z - m4.z); wt.w = __expf(e_keep.w - m4.w);
      den = wt;
      a0.x = wt.x*x_keep.x; a0.y = wt.y*x_keep.x; a0.z = wt.z*x_keep.x; a0.w = wt.w*x_keep.x;
      a1.x = wt.x*x_keep.y; a1.y = wt.y*x_keep.y; a1.z = wt.z*x_keep.y; a1.w = wt.w*x_keep.y;
    }
  } else {
    for (int i = lane; i < deg; i += 64){
      int s = ssrc[start + i];
      float2 xs = ((const float2*)X)[s];
      float4 e;
      e.x = fmaf(xs.x, va.x, fmaf(xs.y, vb.x, ed4.x));
      e.y = fmaf(xs.x, va.y, fmaf(xs.y, vb.y, ed4.y));
      e.z = fmaf(xs.x, va.z, fmaf(xs.y, vb.z, ed4.z));
      e.w = fmaf(xs.x, va.w, fmaf(xs.y, vb.w, ed4.w));
      e.x = fmaxf(e.x, 0.2f*e.x); e.y = fmaxf(e.y, 0.2f*e.y);
      e.z = fmaxf(e.z, 0.2f*e.z); e.w = fmaxf(e.w, 0.2f*e.w);
      float4 wt;
      wt.x = __expf(e.x - m4.x); wt.y = __expf(e.y - m4.y);
      wt.z = __expf(e.z - m4.z); wt.w = __expf(e.w - m4.w);
      den.x += wt.x; den.y += wt.y; den.z += wt.z; den.w += wt.w;
      a0.x = fmaf(wt.x, xs.x, a0.x); a0.y = fmaf(wt.y, xs.x, a0.y);
      a0.z = fmaf(wt.z, xs.x, a0.z); a0.w = fmaf(wt.w, xs.x, a0.w);
      a1.x = fmaf(wt.x, xs.y, a1.x); a1.y = fmaf(wt.y, xs.y, a1.y);
      a1.z = fmaf(wt.z, xs.y, a1.z); a1.w = fmaf(wt.w, xs.y, a1.w);
    }
  }
  wred_sum4(den); wred_sum4(a0); wred_sum4(a1);

  // all lanes hold reductions; epilogue: x1 row (cols 4l..4l+3), head = lane>>4
  int hh = lane >> 4;
  float invd = 1.f / (((hh==0)?den.x:(hh==1)?den.y:(hh==2)?den.z:den.w) + 1e-16f);
  float g0 = ((hh==0)?a0.x:(hh==1)?a0.y:(hh==2)?a0.z:a0.w) * invd;
  float g1 = ((hh==0)?a1.x:(hh==1)?a1.y:(hh==2)?a1.z:a1.w) * invd;
  float4 w0r = ((const float4*)W0)[lane];
  float4 w1r = ((const float4*)(W0 + 256))[lane];
  float4 bb  = ((const float4*)b0)[lane];
  float4 v;
  v.x = fmaxf(fmaf(g0, w0r.x, fmaf(g1, w1r.x, bb.x)), 0.f);
  v.y = fmaxf(fmaf(g0, w0r.y, fmaf(g1, w1r.y, bb.y)), 0.f);
  v.z = fmaxf(fmaf(g0, w0r.z, fmaf(g1, w1r.z, bb.z)), 0.f);
  v.w = fmaxf(fmaf(g0, w0r.w, fmaf(g1, w1r.w, bb.w)), 0.f);
  ((float4*)(X1 + (size_t)n * 256))[lane] = v;
}

// ---------------- L1 GEMM: h1 = x1 @ W1 (split-bf16 MFMA); h1 -> fp16 permuted; ES1/ED1 epilogue ----------------
// Permuted row layout: position p = lr*16 + c holds column c*16 + lr.
__global__ __launch_bounds__(256) void k_l1_mfma(const float* __restrict__ X,
                                                 const u16* __restrict__ WhT, const u16* __restrict__ WlT,
                                                 const float* __restrict__ as_, const float* __restrict__ ad_,
                                                 u16* __restrict__ Hh16, float* __restrict__ ES,
                                                 float* __restrict__ ED, int N){
  __shared__ u16 Ah[64 * 32], Al[64 * 32];
  __shared__ u16 Bh[256 * 32], Bl[256 * 32];
  int t = threadIdx.x;
  int wv = t >> 6, lane = t & 63;
  int lr = lane & 15, lg = lane >> 4;
  int rb = blockIdx.x * 64;

  f32x4 acc[16];
  #pragma unroll
  for (int c = 0; c < 16; c++) acc[c] = (f32x4){0.f, 0.f, 0.f, 0.f};

  int arow = t >> 2, aseg = t & 3;
  int agrow = rb + arow;

  for (int ks = 0; ks < 8; ks++){
    int k0 = ks * 32;
    __syncthreads();
    {
      float xv[8];
      if (agrow < N){
        const float4* p = (const float4*)(X + (size_t)agrow * 256 + k0 + aseg * 8);
        float4 v0 = p[0], v1 = p[1];
        xv[0]=v0.x; xv[1]=v0.y; xv[2]=v0.z; xv[3]=v0.w;
        xv[4]=v1.x; xv[5]=v1.y; xv[6]=v1.z; xv[7]=v1.w;
      } else {
        #pragma unroll
        for (int i = 0; i < 8; i++) xv[i] = 0.f;
      }
      union { u16 us[8]; uint4 v; } ph, pl;
      #pragma unroll
      for (int i = 0; i < 8; i++){
        u16 h = bf16_rne(xv[i]);
        float hf = __uint_as_float(((unsigned int)h) << 16);
        ph.us[i] = h;
        pl.us[i] = bf16_rne(xv[i] - hf);
      }
      *(uint4*)&Ah[arow * 32 + aseg * 8] = ph.v;
      *(uint4*)&Al[arow * 32 + aseg * 8] = pl.v;
    }
    #pragma unroll
    for (int i = 0; i < 4; i++){
      int chunk = i * 256 + t;
      int j = chunk >> 2, seg = chunk & 3;
      *(uint4*)&Bh[j * 32 + seg * 8] = *(const uint4*)&WhT[j * 256 + k0 + seg * 8];
      *(uint4*)&Bl[j * 32 + seg * 8] = *(const uint4*)&WlT[j * 256 + k0 + seg * 8];
    }
    __syncthreads();
    s16x8 ah = *(const s16x8*)&Ah[(wv * 16 + lr) * 32 + lg * 8];
    s16x8 al = *(const s16x8*)&Al[(wv * 16 + lr) * 32 + lg * 8];
    #pragma unroll
    for (int c = 0; c < 16; c++){
      s16x8 bh = *(const s16x8*)&Bh[(c * 16 + lr) * 32 + lg * 8];
      s16x8 bl = *(const s16x8*)&Bl[(c * 16 + lr) * 32 + lg * 8];
      acc[c] = __builtin_amdgcn_mfma_f32_16x16x32_bf16(ah, bh, acc[c], 0, 0, 0);
      acc[c] = __builtin_amdgcn_mfma_f32_16x16x32_bf16(ah, bl, acc[c], 0, 0, 0);
      acc[c] = __builtin_amdgcn_mfma_f32_16x16x32_bf16(al, bh, acc[c], 0, 0, 0);
    }
  }

  // fp16 permuted write: row n, positions lr*16 + c (c=0..15) = cols c*16+lr
  #pragma unroll
  for (int q = 0; q < 4; q++){
    int n = rb + wv * 16 + lg * 4 + q;
    if (n < N){
      union { _Float16 h[16]; uint4 v[2]; } pk;
      #pragma unroll
      for (int c = 0; c < 16; c++) pk.h[c] = (_Float16)acc[c][q];
      uint4* dstp = (uint4*)(Hh16 + (size_t)n * 256 + lr * 16);
      dstp[0] = pk.v[0];
      dstp[1] = pk.v[1];
    }
  }
  // ES1/ED1 from full f32 acc
  float es_p[4][4], ed_p[4][4];
  #pragma unroll
  for (int h = 0; h < 4; h++)
    #pragma unroll
    for (int q = 0; q < 4; q++){ es_p[h][q] = 0.f; ed_p[h][q] = 0.f; }
  #pragma unroll
  for (int c = 0; c < 16; c++){
    float asv = as_[c * 16 + lr];
    float adv = ad_[c * 16 + lr];
    int h = c >> 2;
    #pragma unroll
    for (int q = 0; q < 4; q++){
      es_p[h][q] = fmaf(acc[c][q], asv, es_p[h][q]);
      ed_p[h][q] = fmaf(acc[c][q], adv, ed_p[h][q]);
    }
  }
  #pragma unroll
  for (int h = 0; h < 4; h++)
    #pragma unroll
    for (int q = 0; q < 4; q++){
      #pragma unroll
      for (int mk = 1; mk < 16; mk <<= 1){
        es_p[h][q] += __shfl_xor(es_p[h][q], mk, 64);
        ed_p[h][q] += __shfl_xor(ed_p[h][q], mk, 64);
      }
    }
  if (lr == 0){
    #pragma unroll
    for (int q = 0; q < 4; q++){
      int n = rb + wv * 16 + lg * 4 + q;
      if (n < N){
        #pragma unroll
        for (int h = 0; h < 4; h++){
          ES[n * 4 + h] = es_p[h][q];
          ED[n * 4 + h] = ed_p[h][q];
        }
      }
    }
  }
}

// ---------------- fp16 gather-aggregate helper (permuted layout, 8B/lane) ----------------
__device__ __forceinline__ void agg_rows16(const u16* __restrict__ Hh, const int* ssh, const float* wrow,
                                           int cl, int lane, float* acc){
  union Cv { uint2 u; _Float16 h[4]; };
  int j = 0;
  for (; j + 7 < cl; j += 8){
    Cv r0, r1, r2, r3, r4, r5, r6, r7;
    float w0=wrow[j],w1=wrow[j+1],w2=wrow[j+2],w3=wrow[j+3];
    float w4=wrow[j+4],w5=wrow[j+5],w6=wrow[j+6],w7=wrow[j+7];
    r0.u = *(const uint2*)(Hh + (size_t)ssh[j  ] * 256 + 4*lane);
    r1.u = *(const uint2*)(Hh + (size_t)ssh[j+1] * 256 + 4*lane);
    r2.u = *(const uint2*)(Hh + (size_t)ssh[j+2] * 256 + 4*lane);
    r3.u = *(const uint2*)(Hh + (size_t)ssh[j+3] * 256 + 4*lane);
    r4.u = *(const uint2*)(Hh + (size_t)ssh[j+4] * 256 + 4*lane);
    r5.u = *(const uint2*)(Hh + (size_t)ssh[j+5] * 256 + 4*lane);
    r6.u = *(const uint2*)(Hh + (size_t)ssh[j+6] * 256 + 4*lane);
    r7.u = *(const uint2*)(Hh + (size_t)ssh[j+7] * 256 + 4*lane);
    #pragma unroll
    for (int k = 0; k < 4; k++) acc[k] = fmaf(w0, (float)r0.h[k], acc[k]);
    #pragma unroll
    for (int k = 0; k < 4; k++) acc[k] = fmaf(w1, (float)r1.h[k], acc[k]);
    #pragma unroll
    for (int k = 0; k < 4; k++) acc[k] = fmaf(w2, (float)r2.h[k], acc[k]);
    #pragma unroll
    for (int k = 0; k < 4; k++) acc[k] = fmaf(w3, (float)r3.h[k], acc[k]);
    #pragma unroll
    for (int k = 0; k < 4; k++) acc[k] = fmaf(w4, (float)r4.h[k], acc[k]);
    #pragma unroll
    for (int k = 0; k < 4; k++) acc[k] = fmaf(w5, (float)r5.h[k], acc[k]);
    #pragma unroll
    for (int k = 0; k < 4; k++) acc[k] = fmaf(w6, (float)r6.h[k], acc[k]);
    #pragma unroll
    for (int k = 0; k < 4; k++) acc[k] = fmaf(w7, (float)r7.h[k], acc[k]);
  }
  for (; j + 3 < cl; j += 4){
    Cv r0, r1, r2, r3;
    float w0=wrow[j],w1=wrow[j+1],w2=wrow[j+2],w3=wrow[j+3];
    r0.u = *(const uint2*)(Hh + (size_t)ssh[j  ] * 256 + 4*lane);
    r1.u = *(const uint2*)(Hh + (size_t)ssh[j+1] * 256 + 4*lane);
    r2.u = *(const uint2*)(Hh + (size_t)ssh[j+2] * 256 + 4*lane);
    r3.u = *(const uint2*)(Hh + (size_t)ssh[j+3] * 256 + 4*lane);
    #pragma unroll
    for (int k = 0; k < 4; k++) acc[k] = fmaf(w0, (float)r0.h[k], acc[k]);
    #pragma unroll
    for (int k = 0; k < 4; k++) acc[k] = fmaf(w1, (float)r1.h[k], acc[k]);
    #pragma unroll
    for (int k = 0; k < 4; k++) acc[k] = fmaf(w2, (float)r2.h[k], acc[k]);
    #pragma unroll
    for (int k = 0; k < 4; k++) acc[k] = fmaf(w3, (float)r3.h[k], acc[k]);
  }
  for (; j < cl; ++j){
    Cv r0;
    float w0 = wrow[j];
    r0.u = *(const uint2*)(Hh + (size_t)ssh[j] * 256 + 4*lane);
    #pragma unroll
    for (int k = 0; k < 4; k++) acc[k] = fmaf(w0, (float)r0.h[k], acc[k]);
  }
}

// ---------------- edge1: one WAVE per dst, all 4 heads; epilogue fuses b1+relu+W2 -> P2{h2a,h2b,es2,ed2} ----------------
__global__ __launch_bounds__(256) void k_edge1(const u16* __restrict__ Hh16, const float* __restrict__ ES,
                                               const float* __restrict__ ED, const int* __restrict__ rowptr,
                                               const int* __restrict__ ssrc, const float* __restrict__ b1,
                                               const float* __restrict__ W2,
                                               const float* __restrict__ as2, const float* __restrict__ ad2,
                                               float* __restrict__ P2, int N){
  __shared__ int   ssh[4][64];
  __shared__ float wsh[4][4][68];
  __shared__ int   chmax_sh;
  int wave = threadIdx.x >> 6, lane = threadIdx.x & 63;
  int n = blockIdx.x * 4 + wave;
  bool active = (n < N);
  int myhead = lane & 3;                 // permuted layout: lane covers cols 64(l&3)+16j+(l>>2)
  int start = 0, deg = 0;
  float4 ed4 = make_float4(0.f,0.f,0.f,0.f);
  if (active){
    start = rowptr[n];
    deg   = rowptr[n + 1] - start;
    ed4   = ((const float4*)ED)[n];
  }

  float4 m4 = make_float4(-3.0e38f,-3.0e38f,-3.0e38f,-3.0e38f);
  int    s_keep = 0;
  float4 a_keep = make_float4(0.f,0.f,0.f,0.f);
  for (int i = lane; i < deg; i += 64){
    int s = ssrc[start + i];
    float4 e = ((const float4*)ES)[s];
    e.x += ed4.x; e.y += ed4.y; e.z += ed4.z; e.w += ed4.w;
    e.x = fmaxf(e.x, 0.2f*e.x); e.y = fmaxf(e.y, 0.2f*e.y);
    e.z = fmaxf(e.z, 0.2f*e.z); e.w = fmaxf(e.w, 0.2f*e.w);
    s_keep = s; a_keep = e;
    m4.x = fmaxf(m4.x, e.x); m4.y = fmaxf(m4.y, e.y);
    m4.z = fmaxf(m4.z, e.z); m4.w = fmaxf(m4.w, e.w);
  }
  wred_max4(m4);

  int mych = active ? ((deg + 63) >> 6) : 0;
  if (threadIdx.x == 0) chmax_sh = 0;
  __syncthreads();
  if (lane == 0) atomicMax(&chmax_sh, mych);
  __syncthreads();
  int nch = chmax_sh;

  float accv[4] = {0.f, 0.f, 0.f, 0.f};
  float4 den = make_float4(0.f,0.f,0.f,0.f);

  if (nch == 1){
    float4 wt = make_float4(0.f,0.f,0.f,0.f);
    if (active && lane < deg){
      wt.x = __expf(a_keep.x - m4.x); wt.y = __expf(a_keep.y - m4.y);
      wt.z = __expf(a_keep.z - m4.z); wt.w = __expf(a_keep.w - m4.w);
    }
    den = wt;
    ssh[wave][lane] = s_keep;
    wsh[wave][0][lane] = wt.x; wsh[wave][1][lane] = wt.y;
    wsh[wave][2][lane] = wt.z; wsh[wave][3][lane] = wt.w;
    __syncthreads();
    if (active)
      agg_rows16(Hh16, ssh[wave], wsh[wave][myhead], deg, lane, accv);
    __syncthreads();
  } else {
    for (int c = 0; c < nch; c++){
      int base = c << 6;
      int i = base + lane;
      float4 wt = make_float4(0.f,0.f,0.f,0.f);
      int s = 0;
      if (active && i < deg){
        s = ssrc[start + i];
        float4 e = ((const float4*)ES)[s];
        e.x += ed4.x; e.y += ed4.y; e.z += ed4.z; e.w += ed4.w;
        e.x = fmaxf(e.x, 0.2f*e.x); e.y = fmaxf(e.y, 0.2f*e.y);
        e.z = fmaxf(e.z, 0.2f*e.z); e.w = fmaxf(e.w, 0.2f*e.w);
        wt.x = __expf(e.x - m4.x); wt.y = __expf(e.y - m4.y);
        wt.z = __expf(e.z - m4.z); wt.w = __expf(e.w - m4.w);
      }
      den.x += wt.x; den.y += wt.y; den.z += wt.z; den.w += wt.w;
      ssh[wave][lane] = s;
      wsh[wave][0][lane] = wt.x; wsh[wave][1][lane] = wt.y;
      wsh[wave][2][lane] = wt.z; wsh[wave][3][lane] = wt.w;
      __syncthreads();
      if (active && base < deg)
        agg_rows16(Hh16, ssh[wave], wsh[wave][myhead], min(deg - base, 64), lane, accv);
      __syncthreads();
    }
  }

  if (!active) return;
  wred_sum4(den);
  float d = (myhead==0)?den.x:(myhead==1)?den.y:(myhead==2)?den.z:den.w;
  float inv = 1.f / (d + 1e-16f);
  int c0 = 64 * (lane & 3) + (lane >> 2);   // col_j = c0 + 16j
  float p0 = 0.f, p1 = 0.f;
  #pragma unroll
  for (int j = 0; j < 4; j++){
    int col = c0 + 16 * j;
    float v = fmaxf(fmaf(accv[j], inv, b1[col]), 0.f);
    float2 w2 = ((const float2*)W2)[col];
    p0 = fmaf(v, w2.x, p0);
    p1 = fmaf(v, w2.y, p1);
  }
  p0 = wred_sum(p0); p1 = wred_sum(p1);
  if (lane == 0){
    float4 o;
    o.x = p0; o.y = p1;
    o.z = p0*as2[0] + p1*as2[1];
    o.w = p0*ad2[0] + p1*ad2[1];
    ((float4*)P2)[n] = o;
  }
}

// ---------------- edge2: H=1, O=2; P2 = {h2a,h2b,es2,ed2}; single 16B gather + fast path ----------------
__global__ __launch_bounds__(256) void k_edge2(const float* __restrict__ P2, const int* __restrict__ rowptr,
                                               const int* __restrict__ ssrc, const float* __restrict__ bias,
                                               float* __restrict__ Out, int N){
  int lane = threadIdx.x & 63;
  int n = blockIdx.x * 4 + (threadIdx.x >> 6);
  if (n >= N) return;
  int start = rowptr[n], deg = rowptr[n + 1] - start;
  float edn = ((const float4*)P2)[n].w;
  float m = -3.0e38f;
  float4 p_keep = make_float4(0.f,0.f,0.f,0.f);
  float  e_keep = 0.f;
  for (int i = lane; i < deg; i += 64){
    int s = ssrc[start + i];
    float4 p = ((const float4*)P2)[s];
    float a = p.z + edn; a = fmaxf(a, 0.2f * a);
    p_keep = p; e_keep = a;
    m = fmaxf(m, a);
  }
  #pragma unroll
  for (int mk = 32; mk > 0; mk >>= 1) m = fmaxf(m, __shfl_xor(m, mk, 64));

  float den = 0.f, a0 = 0.f, a1 = 0.f;
  if (deg <= 64){
    if (lane < deg){
      float w = __expf(e_keep - m);
      den = w; a0 = w * p_keep.x; a1 = w * p_keep.y;
    }
  } else {
    for (int i = lane; i < deg; i += 64){
      int s = ssrc[start + i];
      float4 p = ((const float4*)P2)[s];
      float a = p.z + edn; a = fmaxf(a, 0.2f * a);
      float w = __expf(a - m);
      den += w;
      a0 = fmaf(w, p.x, a0);
      a1 = fmaf(w, p.y, a1);
    }
  }
  den = wred_sum(den); a0 = wred_sum(a0); a1 = wred_sum(a1);
  if (lane == 0){
    float inv = 1.f / (den + 1e-16f);
    Out[n*2]     = fmaxf(a0 * inv + bias[0], 0.f);
    Out[n*2 + 1] = fmaxf(a1 * inv + bias[1], 0.f);
  }
}

extern "C" void kernel_launch(void* const* d_in, const int* in_sizes, int n_in,
                              void* d_out, int out_size, void* d_ws, size_t ws_size,
                              hipStream_t stream) {
  const float* x   = (const float*)d_in[0];
  const int*   ei  = (const int*)  d_in[1];
  const float* W0  = (const float*)d_in[2];
  const float* as0 = (const float*)d_in[3];
  const float* ad0 = (const float*)d_in[4];
  const float* b0  = (const float*)d_in[5];
  const float* W1  = (const float*)d_in[6];
  const float* as1 = (const float*)d_in[7];
  const float* ad1 = (const float*)d_in[8];
  const float* b1  = (const float*)d_in[9];
  const float* W2  = (const float*)d_in[10];
  const float* as2 = (const float*)d_in[11];
  const float* ad2 = (const float*)d_in[12];
  const float* b2  = (const float*)d_in[13];

  int N = in_sizes[0] / 2;
  int E = in_sizes[1] / 2;
  const int* src = ei;
  const int* dst = ei + E;

  char* ws = (char*)d_ws;
  size_t off = 0;
  auto alc = [&](size_t bytes){ size_t o = off; off += (bytes + 255) & ~(size_t)255; return o; };
  int*   deg    = (int*)(ws + alc((size_t)N * 4));
  int*   rowptr = (int*)(ws + alc((size_t)(N + 1) * 4));
  int*   cursor = (int*)(ws + alc((size_t)N * 4));
  int*   ssrc   = (int*)(ws + alc((size_t)(E + N) * 4));
  float* X1     = (float*)(ws + alc((size_t)N * 256 * 4));
  u16*   Hh16   = (u16*)  (ws + alc((size_t)N * 256 * 2));
  float* es1    = (float*)(ws + alc((size_t)N * 4 * 4));
  float* ed1    = (float*)(ws + alc((size_t)N * 4 * 4));
  float* P2     = (float*)(ws + alc((size_t)N * 4 * 4));
  u16*   wht    = (u16*)  (ws + alc((size_t)256 * 256 * 2));
  u16*   wlt    = (u16*)  (ws + alc((size_t)256 * 256 * 2));
  float* vs     = (float*)(ws + alc(16 * 4));
  int*   bsum   = (int*)(ws + alc(64 * 4));
  int*   boff   = (int*)(ws + alc(65 * 4));
  float* out    = (float*)d_out;

  int nblk_deg = (N + 255) / 256;
  int nb = (N + 2047) / 2048;    // scan blocks (<=64)

  k_setup     <<<nblk_deg + 257, 256, 0, stream>>>(W1, wht, wlt, W0, as0, ad0, vs, deg, N, nblk_deg);
  k_hist      <<<(E + 255)/256, 256, 0, stream>>>(dst, E, deg);
  k_scan_local<<<nb, 256, 0, stream>>>(deg, rowptr, bsum, N);
  k_boff      <<<1, 64, 0, stream>>>(bsum, boff, nb);
  k_finish    <<<nblk_deg, 256, 0, stream>>>(rowptr, boff, ssrc, cursor, N, nb);
  k_scatter   <<<(E + 255)/256, 256, 0, stream>>>(src, dst, E, cursor, ssrc);

  k_edge0  <<<(N + 3)/4, 256, 0, stream>>>(x, vs, W0, b0, rowptr, ssrc, X1, N);
  k_l1_mfma<<<(N + 63)/64, 256, 0, stream>>>(X1, wht, wlt, as1, ad1, Hh16, es1, ed1, N);
  k_edge1  <<<(N + 3)/4, 256, 0, stream>>>(Hh16, es1, ed1, rowptr, ssrc, b1, W2, as2, ad2, P2, N);
  k_edge2  <<<(N + 3)/4, 256, 0, stream>>>(P2, rowptr, ssrc, b2, out, N);
}

// Round 9
// 340.501 us; speedup vs baseline: 1.4763x; 1.1163x over previous
//
#include <hip/hip_runtime.h>
#include <math.h>

// 3-layer GAT, N=50000, E=800000 (+N self loops).
// L0 collapsed to 2-dim aggregation; L1 GEMM (split-bf16 MFMA) before aggregation;
// h1 stored fp16 in a permuted row layout; L2 projection fused into edge1 epilogue.
// Softmax computed WITHOUT max subtraction (shift invariance; |e| << 88 so no overflow),
// which removes one full gather pass + two reduce chains per edge kernel.
// k_edge1 runs one 64-thread block per node (no cross-wave coupling).

typedef __attribute__((ext_vector_type(8))) short s16x8;
typedef __attribute__((ext_vector_type(4))) float f32x4;
typedef unsigned short u16;

__device__ __forceinline__ float wred_sum(float v){
  #pragma unroll
  for (int m = 32; m > 0; m >>= 1) v += __shfl_xor(v, m, 64);
  return v;
}
__device__ __forceinline__ void wred_sum4(float4& v){
  #pragma unroll
  for (int m = 32; m > 0; m >>= 1){
    v.x += __shfl_xor(v.x, m, 64);
    v.y += __shfl_xor(v.y, m, 64);
    v.z += __shfl_xor(v.z, m, 64);
    v.w += __shfl_xor(v.w, m, 64);
  }
}
__device__ __forceinline__ u16 bf16_rne(float x){
  unsigned int u = __float_as_uint(x);
  unsigned int r = u + 0x7FFFu + ((u >> 16) & 1u);
  return (u16)(r >> 16);
}

// ---------------- setup: deg init + W1 hi/lo transpose-convert + vs(=W0@a0) prep ----------------
__global__ __launch_bounds__(256) void k_setup(const float* __restrict__ W1, u16* __restrict__ WhT,
                                               u16* __restrict__ WlT,
                                               const float* __restrict__ W0, const float* __restrict__ as0,
                                               const float* __restrict__ ad0, float* __restrict__ vs,
                                               int* __restrict__ deg, int N, int nblk_deg){
  int b = blockIdx.x;
  if (b < nblk_deg){
    int i = b * 256 + threadIdx.x;
    if (i < N) deg[i] = 1;            // self loop
  } else if (b < nblk_deg + 256){
    int k = b - nblk_deg, j = threadIdx.x;
    float w = W1[k * 256 + j];
    u16 h = bf16_rne(w);
    float hf = __uint_as_float(((unsigned int)h) << 16);
    WhT[j * 256 + k] = h;
    WlT[j * 256 + k] = bf16_rne(w - hf);
  } else {
    int t = threadIdx.x;
    if (t < 8){
      int j = t >> 2, h = t & 3;
      float ss = 0.f, dd = 0.f;
      #pragma unroll 8
      for (int o = 0; o < 64; o++){
        float w = W0[j * 256 + h * 64 + o];
        ss = fmaf(w, as0[h * 64 + o], ss);
        dd = fmaf(w, ad0[h * 64 + o], dd);
      }
      vs[j * 4 + h]     = ss;   // src proj
      vs[8 + j * 4 + h] = dd;   // dst proj
    }
  }
}

__global__ __launch_bounds__(256) void k_hist(const int* __restrict__ dst, int E, int* deg){
  int e = blockIdx.x * 256 + threadIdx.x;
  if (e < E) atomicAdd(&deg[dst[e]], 1);
}

// ---------------- 3-level scan: local (2048/block) -> block offsets -> finish ----------------
__global__ __launch_bounds__(256) void k_scan_local(const int* __restrict__ deg, int* __restrict__ rowptr,
                                                    int* __restrict__ bsum, int N){
  __shared__ int sb[256];
  int t = threadIdx.x;
  int base = blockIdx.x * 2048 + t * 8;
  int d[8], s = 0;
  #pragma unroll
  for (int k = 0; k < 8; k++){
    d[k] = (base + k < N) ? deg[base + k] : 0;
    s += d[k];
  }
  sb[t] = s;
  __syncthreads();
  for (int off = 1; off < 256; off <<= 1){
    int v = (t >= off) ? sb[t - off] : 0;
    __syncthreads();
    sb[t] += v;
    __syncthreads();
  }
  int run = (t == 0) ? 0 : sb[t - 1];
  #pragma unroll
  for (int k = 0; k < 8; k++){
    if (base + k < N) rowptr[base + k] = run;
    run += d[k];
  }
  if (t == 255) bsum[blockIdx.x] = sb[255];
}

__global__ __launch_bounds__(64) void k_boff(const int* __restrict__ bsum, int* __restrict__ boff, int nb){
  __shared__ int sb[64];
  int t = threadIdx.x;
  int v = (t < nb) ? bsum[t] : 0;
  sb[t] = v;
  __syncthreads();
  for (int off = 1; off < 64; off <<= 1){
    int u = (t >= off) ? sb[t - off] : 0;
    __syncthreads();
    sb[t] += u;
    __syncthreads();
  }
  boff[t] = (t == 0) ? 0 : sb[t - 1];
  if (t == nb - 1) boff[nb] = sb[nb - 1];   // grand total
}

__global__ __launch_bounds__(256) void k_finish(int* __restrict__ rowptr, const int* __restrict__ boff,
                                                int* __restrict__ ssrc, int* __restrict__ cursor,
                                                int N, int nb){
  int i = blockIdx.x * 256 + threadIdx.x;
  if (i < N){
    int p = rowptr[i] + boff[i >> 11];
    rowptr[i] = p;
    ssrc[p] = i;          // self loop first in segment
    cursor[i] = p + 1;
  }
  if (i == 0) rowptr[N] = boff[nb];
}

__global__ __launch_bounds__(256) void k_scatter(const int* __restrict__ src, const int* __restrict__ dst,
                                                 int E, int* cursor, int* ssrc){
  int e = blockIdx.x * 256 + threadIdx.x;
  if (e < E){ int p = atomicAdd(&cursor[dst[e]], 1); ssrc[p] = src[e]; }
}

// ---------------- edge0: 2-dim aggregation, single pass (no max); epilogue x1 = relu(agg@W0+b0) ----------------
__global__ __launch_bounds__(256) void k_edge0(const float* __restrict__ X, const float* __restrict__ vs,
                                               const float* __restrict__ W0, const float* __restrict__ b0,
                                               const int* __restrict__ rowptr, const int* __restrict__ ssrc,
                                               float* __restrict__ X1, int N){
  int lane = threadIdx.x & 63;
  int n = blockIdx.x * 4 + (threadIdx.x >> 6);
  if (n >= N) return;
  int start = rowptr[n], deg = rowptr[n + 1] - start;
  float4 va = ((const float4*)vs)[0], vb = ((const float4*)vs)[1];   // src coeffs for x0,x1
  float4 vc = ((const float4*)vs)[2], vd = ((const float4*)vs)[3];   // dst coeffs
  float2 xn = ((const float2*)X)[n];
  float4 ed4;
  ed4.x = fmaf(xn.x, vc.x, xn.y * vd.x); ed4.y = fmaf(xn.x, vc.y, xn.y * vd.y);
  ed4.z = fmaf(xn.x, vc.z, xn.y * vd.z); ed4.w = fmaf(xn.x, vc.w, xn.y * vd.w);

  float4 den = make_float4(0.f,0.f,0.f,0.f);
  float4 a0  = make_float4(0.f,0.f,0.f,0.f);
  float4 a1  = make_float4(0.f,0.f,0.f,0.f);
  for (int i = lane; i < deg; i += 64){
    int s = ssrc[start + i];
    float2 xs = ((const float2*)X)[s];
    float4 e;
    e.x = fmaf(xs.x, va.x, fmaf(xs.y, vb.x, ed4.x));
    e.y = fmaf(xs.x, va.y, fmaf(xs.y, vb.y, ed4.y));
    e.z = fmaf(xs.x, va.z, fmaf(xs.y, vb.z, ed4.z));
    e.w = fmaf(xs.x, va.w, fmaf(xs.y, vb.w, ed4.w));
    e.x = fmaxf(e.x, 0.2f*e.x); e.y = fmaxf(e.y, 0.2f*e.y);
    e.z = fmaxf(e.z, 0.2f*e.z); e.w = fmaxf(e.w, 0.2f*e.w);
    float4 wt;
    wt.x = __expf(e.x); wt.y = __expf(e.y);
    wt.z = __expf(e.z); wt.w = __expf(e.w);
    den.x += wt.x; den.y += wt.y; den.z += wt.z; den.w += wt.w;
    a0.x = fmaf(wt.x, xs.x, a0.x); a0.y = fmaf(wt.y, xs.x, a0.y);
    a0.z = fmaf(wt.z, xs.x, a0.z); a0.w = fmaf(wt.w, xs.x, a0.w);
    a1.x = fmaf(wt.x, xs.y, a1.x); a1.y = fmaf(wt.y, xs.y, a1.y);
    a1.z = fmaf(wt.z, xs.y, a1.z); a1.w = fmaf(wt.w, xs.y, a1.w);
  }
  wred_sum4(den); wred_sum4(a0); wred_sum4(a1);

  // epilogue: x1 row (cols 4l..4l+3), head = lane>>4
  int hh = lane >> 4;
  float invd = 1.f / (((hh==0)?den.x:(hh==1)?den.y:(hh==2)?den.z:den.w) + 1e-16f);
  float g0 = ((hh==0)?a0.x:(hh==1)?a0.y:(hh==2)?a0.z:a0.w) * invd;
  float g1 = ((hh==0)?a1.x:(hh==1)?a1.y:(hh==2)?a1.z:a1.w) * invd;
  float4 w0r = ((const float4*)W0)[lane];
  float4 w1r = ((const float4*)(W0 + 256))[lane];
  float4 bb  = ((const float4*)b0)[lane];
  float4 v;
  v.x = fmaxf(fmaf(g0, w0r.x, fmaf(g1, w1r.x, bb.x)), 0.f);
  v.y = fmaxf(fmaf(g0, w0r.y, fmaf(g1, w1r.y, bb.y)), 0.f);
  v.z = fmaxf(fmaf(g0, w0r.z, fmaf(g1, w1r.z, bb.z)), 0.f);
  v.w = fmaxf(fmaf(g0, w0r.w, fmaf(g1, w1r.w, bb.w)), 0.f);
  ((float4*)(X1 + (size_t)n * 256))[lane] = v;
}

// ---------------- L1 GEMM: h1 = x1 @ W1 (split-bf16 MFMA); h1 -> fp16 permuted; ES1/ED1 epilogue ----------------
// Permuted row layout: position p = lr*16 + c holds column c*16 + lr.
__global__ __launch_bounds__(256) void k_l1_mfma(const float* __restrict__ X,
                                                 const u16* __restrict__ WhT, const u16* __restrict__ WlT,
                                                 const float* __restrict__ as_, const float* __restrict__ ad_,
                                                 u16* __restrict__ Hh16, float* __restrict__ ES,
                                                 float* __restrict__ ED, int N){
  __shared__ u16 Ah[64 * 32], Al[64 * 32];
  __shared__ u16 Bh[256 * 32], Bl[256 * 32];
  int t = threadIdx.x;
  int wv = t >> 6, lane = t & 63;
  int lr = lane & 15, lg = lane >> 4;
  int rb = blockIdx.x * 64;

  f32x4 acc[16];
  #pragma unroll
  for (int c = 0; c < 16; c++) acc[c] = (f32x4){0.f, 0.f, 0.f, 0.f};

  int arow = t >> 2, aseg = t & 3;
  int agrow = rb + arow;

  for (int ks = 0; ks < 8; ks++){
    int k0 = ks * 32;
    __syncthreads();
    {
      float xv[8];
      if (agrow < N){
        const float4* p = (const float4*)(X + (size_t)agrow * 256 + k0 + aseg * 8);
        float4 v0 = p[0], v1 = p[1];
        xv[0]=v0.x; xv[1]=v0.y; xv[2]=v0.z; xv[3]=v0.w;
        xv[4]=v1.x; xv[5]=v1.y; xv[6]=v1.z; xv[7]=v1.w;
      } else {
        #pragma unroll
        for (int i = 0; i < 8; i++) xv[i] = 0.f;
      }
      union { u16 us[8]; uint4 v; } ph, pl;
      #pragma unroll
      for (int i = 0; i < 8; i++){
        u16 h = bf16_rne(xv[i]);
        float hf = __uint_as_float(((unsigned int)h) << 16);
        ph.us[i] = h;
        pl.us[i] = bf16_rne(xv[i] - hf);
      }
      *(uint4*)&Ah[arow * 32 + aseg * 8] = ph.v;
      *(uint4*)&Al[arow * 32 + aseg * 8] = pl.v;
    }
    #pragma unroll
    for (int i = 0; i < 4; i++){
      int chunk = i * 256 + t;
      int j = chunk >> 2, seg = chunk & 3;
      *(uint4*)&Bh[j * 32 + seg * 8] = *(const uint4*)&WhT[j * 256 + k0 + seg * 8];
      *(uint4*)&Bl[j * 32 + seg * 8] = *(const uint4*)&WlT[j * 256 + k0 + seg * 8];
    }
    __syncthreads();
    s16x8 ah = *(const s16x8*)&Ah[(wv * 16 + lr) * 32 + lg * 8];
    s16x8 al = *(const s16x8*)&Al[(wv * 16 + lr) * 32 + lg * 8];
    #pragma unroll
    for (int c = 0; c < 16; c++){
      s16x8 bh = *(const s16x8*)&Bh[(c * 16 + lr) * 32 + lg * 8];
      s16x8 bl = *(const s16x8*)&Bl[(c * 16 + lr) * 32 + lg * 8];
      acc[c] = __builtin_amdgcn_mfma_f32_16x16x32_bf16(ah, bh, acc[c], 0, 0, 0);
      acc[c] = __builtin_amdgcn_mfma_f32_16x16x32_bf16(ah, bl, acc[c], 0, 0, 0);
      acc[c] = __builtin_amdgcn_mfma_f32_16x16x32_bf16(al, bh, acc[c], 0, 0, 0);
    }
  }

  // fp16 permuted write: row n, positions lr*16 + c (c=0..15) = cols c*16+lr
  #pragma unroll
  for (int q = 0; q < 4; q++){
    int n = rb + wv * 16 + lg * 4 + q;
    if (n < N){
      union { _Float16 h[16]; uint4 v[2]; } pk;
      #pragma unroll
      for (int c = 0; c < 16; c++) pk.h[c] = (_Float16)acc[c][q];
      uint4* dstp = (uint4*)(Hh16 + (size_t)n * 256 + lr * 16);
      dstp[0] = pk.v[0];
      dstp[1] = pk.v[1];
    }
  }
  // ES1/ED1 from full f32 acc
  float es_p[4][4], ed_p[4][4];
  #pragma unroll
  for (int h = 0; h < 4; h++)
    #pragma unroll
    for (int q = 0; q < 4; q++){ es_p[h][q] = 0.f; ed_p[h][q] = 0.f; }
  #pragma unroll
  for (int c = 0; c < 16; c++){
    float asv = as_[c * 16 + lr];
    float adv = ad_[c * 16 + lr];
    int h = c >> 2;
    #pragma unroll
    for (int q = 0; q < 4; q++){
      es_p[h][q] = fmaf(acc[c][q], asv, es_p[h][q]);
      ed_p[h][q] = fmaf(acc[c][q], adv, ed_p[h][q]);
    }
  }
  #pragma unroll
  for (int h = 0; h < 4; h++)
    #pragma unroll
    for (int q = 0; q < 4; q++){
      #pragma unroll
      for (int mk = 1; mk < 16; mk <<= 1){
        es_p[h][q] += __shfl_xor(es_p[h][q], mk, 64);
        ed_p[h][q] += __shfl_xor(ed_p[h][q], mk, 64);
      }
    }
  if (lr == 0){
    #pragma unroll
    for (int q = 0; q < 4; q++){
      int n = rb + wv * 16 + lg * 4 + q;
      if (n < N){
        #pragma unroll
        for (int h = 0; h < 4; h++){
          ES[n * 4 + h] = es_p[h][q];
          ED[n * 4 + h] = ed_p[h][q];
        }
      }
    }
  }
}

// ---------------- fp16 gather-aggregate helper (permuted layout, 8B/lane) ----------------
__device__ __forceinline__ void agg_rows16(const u16* __restrict__ Hh, const int* ssh, const float* wrow,
                                           int cl, int lane, float* acc){
  union Cv { uint2 u; _Float16 h[4]; };
  int j = 0;
  for (; j + 7 < cl; j += 8){
    Cv r0, r1, r2, r3, r4, r5, r6, r7;
    float w0=wrow[j],w1=wrow[j+1],w2=wrow[j+2],w3=wrow[j+3];
    float w4=wrow[j+4],w5=wrow[j+5],w6=wrow[j+6],w7=wrow[j+7];
    r0.u = *(const uint2*)(Hh + (size_t)ssh[j  ] * 256 + 4*lane);
    r1.u = *(const uint2*)(Hh + (size_t)ssh[j+1] * 256 + 4*lane);
    r2.u = *(const uint2*)(Hh + (size_t)ssh[j+2] * 256 + 4*lane);
    r3.u = *(const uint2*)(Hh + (size_t)ssh[j+3] * 256 + 4*lane);
    r4.u = *(const uint2*)(Hh + (size_t)ssh[j+4] * 256 + 4*lane);
    r5.u = *(const uint2*)(Hh + (size_t)ssh[j+5] * 256 + 4*lane);
    r6.u = *(const uint2*)(Hh + (size_t)ssh[j+6] * 256 + 4*lane);
    r7.u = *(const uint2*)(Hh + (size_t)ssh[j+7] * 256 + 4*lane);
    #pragma unroll
    for (int k = 0; k < 4; k++) acc[k] = fmaf(w0, (float)r0.h[k], acc[k]);
    #pragma unroll
    for (int k = 0; k < 4; k++) acc[k] = fmaf(w1, (float)r1.h[k], acc[k]);
    #pragma unroll
    for (int k = 0; k < 4; k++) acc[k] = fmaf(w2, (float)r2.h[k], acc[k]);
    #pragma unroll
    for (int k = 0; k < 4; k++) acc[k] = fmaf(w3, (float)r3.h[k], acc[k]);
    #pragma unroll
    for (int k = 0; k < 4; k++) acc[k] = fmaf(w4, (float)r4.h[k], acc[k]);
    #pragma unroll
    for (int k = 0; k < 4; k++) acc[k] = fmaf(w5, (float)r5.h[k], acc[k]);
    #pragma unroll
    for (int k = 0; k < 4; k++) acc[k] = fmaf(w6, (float)r6.h[k], acc[k]);
    #pragma unroll
    for (int k = 0; k < 4; k++) acc[k] = fmaf(w7, (float)r7.h[k], acc[k]);
  }
  for (; j + 3 < cl; j += 4){
    Cv r0, r1, r2, r3;
    float w0=wrow[j],w1=wrow[j+1],w2=wrow[j+2],w3=wrow[j+3];
    r0.u = *(const uint2*)(Hh + (size_t)ssh[j  ] * 256 + 4*lane);
    r1.u = *(const uint2*)(Hh + (size_t)ssh[j+1] * 256 + 4*lane);
    r2.u = *(const uint2*)(Hh + (size_t)ssh[j+2] * 256 + 4*lane);
    r3.u = *(const uint2*)(Hh + (size_t)ssh[j+3] * 256 + 4*lane);
    #pragma unroll
    for (int k = 0; k < 4; k++) acc[k] = fmaf(w0, (float)r0.h[k], acc[k]);
    #pragma unroll
    for (int k = 0; k < 4; k++) acc[k] = fmaf(w1, (float)r1.h[k], acc[k]);
    #pragma unroll
    for (int k = 0; k < 4; k++) acc[k] = fmaf(w2, (float)r2.h[k], acc[k]);
    #pragma unroll
    for (int k = 0; k < 4; k++) acc[k] = fmaf(w3, (float)r3.h[k], acc[k]);
  }
  for (; j < cl; ++j){
    Cv r0;
    float w0 = wrow[j];
    r0.u = *(const uint2*)(Hh + (size_t)ssh[j] * 256 + 4*lane);
    #pragma unroll
    for (int k = 0; k < 4; k++) acc[k] = fmaf(w0, (float)r0.h[k], acc[k]);
  }
}

// ---------------- edge1: ONE 64-thread block per dst node; no max pass; epilogue fuses b1+relu+W2 -> P2 ----------------
__global__ __launch_bounds__(64) void k_edge1(const u16* __restrict__ Hh16, const float* __restrict__ ES,
                                              const float* __restrict__ ED, const int* __restrict__ rowptr,
                                              const int* __restrict__ ssrc, const float* __restrict__ b1,
                                              const float* __restrict__ W2,
                                              const float* __restrict__ as2, const float* __restrict__ ad2,
                                              float* __restrict__ P2, int N){
  __shared__ int   ssh[64];
  __shared__ float wsh[4][68];
  int lane = threadIdx.x;
  int n = blockIdx.x;
  int myhead = lane & 3;                 // permuted layout: lane covers cols 64(l&3)+16j+(l>>2)
  int start = rowptr[n], deg = rowptr[n + 1] - start;
  float4 ed4 = ((const float4*)ED)[n];

  float accv[4] = {0.f, 0.f, 0.f, 0.f};
  float4 den = make_float4(0.f,0.f,0.f,0.f);

  for (int base = 0; base < deg; base += 64){
    int i = base + lane;
    float4 wt = make_float4(0.f,0.f,0.f,0.f);
    int s = 0;
    if (i < deg){
      s = ssrc[start + i];
      float4 e = ((const float4*)ES)[s];
      e.x += ed4.x; e.y += ed4.y; e.z += ed4.z; e.w += ed4.w;
      e.x = fmaxf(e.x, 0.2f*e.x); e.y = fmaxf(e.y, 0.2f*e.y);
      e.z = fmaxf(e.z, 0.2f*e.z); e.w = fmaxf(e.w, 0.2f*e.w);
      wt.x = __expf(e.x); wt.y = __expf(e.y);
      wt.z = __expf(e.z); wt.w = __expf(e.w);
    }
    den.x += wt.x; den.y += wt.y; den.z += wt.z; den.w += wt.w;
    ssh[lane] = s;
    wsh[0][lane] = wt.x; wsh[1][lane] = wt.y;
    wsh[2][lane] = wt.z; wsh[3][lane] = wt.w;
    __syncthreads();
    agg_rows16(Hh16, ssh, wsh[myhead], min(deg - base, 64), lane, accv);
    __syncthreads();
  }

  wred_sum4(den);
  float d = (myhead==0)?den.x:(myhead==1)?den.y:(myhead==2)?den.z:den.w;
  float inv = 1.f / (d + 1e-16f);
  int c0 = 64 * (lane & 3) + (lane >> 2);   // col_j = c0 + 16j
  float p0 = 0.f, p1 = 0.f;
  #pragma unroll
  for (int j = 0; j < 4; j++){
    int col = c0 + 16 * j;
    float v = fmaxf(fmaf(accv[j], inv, b1[col]), 0.f);
    float2 w2 = ((const float2*)W2)[col];
    p0 = fmaf(v, w2.x, p0);
    p1 = fmaf(v, w2.y, p1);
  }
  p0 = wred_sum(p0); p1 = wred_sum(p1);
  if (lane == 0){
    float4 o;
    o.x = p0; o.y = p1;
    o.z = p0*as2[0] + p1*as2[1];
    o.w = p0*ad2[0] + p1*ad2[1];
    ((float4*)P2)[n] = o;
  }
}

// ---------------- edge2: H=1, O=2; P2 = {h2a,h2b,es2,ed2}; single pass, no max ----------------
__global__ __launch_bounds__(256) void k_edge2(const float* __restrict__ P2, const int* __restrict__ rowptr,
                                               const int* __restrict__ ssrc, const float* __restrict__ bias,
                                               float* __restrict__ Out, int N){
  int lane = threadIdx.x & 63;
  int n = blockIdx.x * 4 + (threadIdx.x >> 6);
  if (n >= N) return;
  int start = rowptr[n], deg = rowptr[n + 1] - start;
  float edn = ((const float4*)P2)[n].w;
  float den = 0.f, a0 = 0.f, a1 = 0.f;
  for (int i = lane; i < deg; i += 64){
    int s = ssrc[start + i];
    float4 p = ((const float4*)P2)[s];
    float a = p.z + edn; a = fmaxf(a, 0.2f * a);
    float w = __expf(a);
    den += w;
    a0 = fmaf(w, p.x, a0);
    a1 = fmaf(w, p.y, a1);
  }
  den = wred_sum(den); a0 = wred_sum(a0); a1 = wred_sum(a1);
  if (lane == 0){
    float inv = 1.f / (den + 1e-16f);
    Out[n*2]     = fmaxf(a0 * inv + bias[0], 0.f);
    Out[n*2 + 1] = fmaxf(a1 * inv + bias[1], 0.f);
  }
}

extern "C" void kernel_launch(void* const* d_in, const int* in_sizes, int n_in,
                              void* d_out, int out_size, void* d_ws, size_t ws_size,
                              hipStream_t stream) {
  const float* x   = (const float*)d_in[0];
  const int*   ei  = (const int*)  d_in[1];
  const float* W0  = (const float*)d_in[2];
  const float* as0 = (const float*)d_in[3];
  const float* ad0 = (const float*)d_in[4];
  const float* b0  = (const float*)d_in[5];
  const float* W1  = (const float*)d_in[6];
  const float* as1 = (const float*)d_in[7];
  const float* ad1 = (const float*)d_in[8];
  const float* b1  = (const float*)d_in[9];
  const float* W2  = (const float*)d_in[10];
  const float* as2 = (const float*)d_in[11];
  const float* ad2 = (const float*)d_in[12];
  const float* b2  = (const float*)d_in[13];

  int N = in_sizes[0] / 2;
  int E = in_sizes[1] / 2;
  const int* src = ei;
  const int* dst = ei + E;

  char* ws = (char*)d_ws;
  size_t off = 0;
  auto alc = [&](size_t bytes){ size_t o = off; off += (bytes + 255) & ~(size_t)255; return o; };
  int*   deg    = (int*)(ws + alc((size_t)N * 4));
  int*   rowptr = (int*)(ws + alc((size_t)(N + 1) * 4));
  int*   cursor = (int*)(ws + alc((size_t)N * 4));
  int*   ssrc   = (int*)(ws + alc((size_t)(E + N) * 4));
  float* X1     = (float*)(ws + alc((size_t)N * 256 * 4));
  u16*   Hh16   = (u16*)  (ws + alc((size_t)N * 256 * 2));
  float* es1    = (float*)(ws + alc((size_t)N * 4 * 4));
  float* ed1    = (float*)(ws + alc((size_t)N * 4 * 4));
  float* P2     = (float*)(ws + alc((size_t)N * 4 * 4));
  u16*   wht    = (u16*)  (ws + alc((size_t)256 * 256 * 2));
  u16*   wlt    = (u16*)  (ws + alc((size_t)256 * 256 * 2));
  float* vs     = (float*)(ws + alc(16 * 4));
  int*   bsum   = (int*)(ws + alc(64 * 4));
  int*   boff   = (int*)(ws + alc(65 * 4));
  float* out    = (float*)d_out;

  int nblk_deg = (N + 255) / 256;
  int nb = (N + 2047) / 2048;    // scan blocks (<=64)

  k_setup     <<<nblk_deg + 257, 256, 0, stream>>>(W1, wht, wlt, W0, as0, ad0, vs, deg, N, nblk_deg);
  k_hist      <<<(E + 255)/256, 256, 0, stream>>>(dst, E, deg);
  k_scan_local<<<nb, 256, 0, stream>>>(deg, rowptr, bsum, N);
  k_boff      <<<1, 64, 0, stream>>>(bsum, boff, nb);
  k_finish    <<<nblk_deg, 256, 0, stream>>>(rowptr, boff, ssrc, cursor, N, nb);
  k_scatter   <<<(E + 255)/256, 256, 0, stream>>>(src, dst, E, cursor, ssrc);

  k_edge0  <<<(N + 3)/4, 256, 0, stream>>>(x, vs, W0, b0, rowptr, ssrc, X1, N);
  k_l1_mfma<<<(N + 63)/64, 256, 0, stream>>>(X1, wht, wlt, as1, ad1, Hh16, es1, ed1, N);
  k_edge1  <<<N, 64, 0, stream>>>(Hh16, es1, ed1, rowptr, ssrc, b1, W2, as2, ad2, P2, N);
  k_edge2  <<<(N + 3)/4, 256, 0, stream>>>(P2, rowptr, ssrc, b2, out, N);
}